// Round 4
// baseline (209.573 us; speedup 1.0000x reference)
//
#include <hip/hip_runtime.h>

// YOLOv1 loss, fused. Split by data character:
//  - channels 10..29 (2/3 of bytes): pure streaming float2 loads, obj from LDS
//  - channels 0..9 (boxes/conf): staged to LDS once, per-cell compute
// pred, labels: [B=16384, C=30, G=7, G=7] fp32. Output: scalar fp32.

constexpr int BATCH  = 16384;
constexpr int G      = 7;
constexpr int GG     = G * G;          // 49
constexpr int IMG_F  = 30 * GG;        // 1470 floats per image per tensor
constexpr int TPB    = 256;
constexpr int NIMG   = 8;              // images per block
constexpr int NBLK   = BATCH / NIMG;   // 2048
constexpr int BOX_F  = 10 * GG;        // 490 floats staged per image per tensor
constexpr int BOX_V2 = BOX_F / 2;      // 245 float2
constexpr int IMG_V2 = IMG_F / 2;      // 735 float2
constexpr int CLS_V2 = IMG_V2 - BOX_V2;// 490 float2 in cls region per image
constexpr int STAGE_TOT = 2 * NIMG * BOX_V2;     // 3920 float2 to stage
constexpr int STAGE_FULL = STAGE_TOT / TPB;      // 15
constexpr int STAGE_TAIL = STAGE_TOT - STAGE_FULL * TPB;  // 80
constexpr int NCELL  = NIMG * GG;      // 392 cells per block

__device__ __forceinline__ float sq(float x) { return x * x; }

// Box-part loss for one cell (everything except the cls term), from LDS.
__device__ __forceinline__ float cell_box_loss(
    const float* __restrict__ sp,   // sbox_p[img], 490 floats
    const float* __restrict__ sl,   // sbox_l[img]
    int cell)
{
    const int m = cell / G;
    const int n = cell - m * G;

    float pv[10];
#pragma unroll
    for (int c = 0; c < 10; ++c) pv[c] = sp[c * GG + cell];
    float lv[9];
#pragma unroll
    for (int c = 0; c < 9; ++c) lv[c] = sl[c * GG + cell];

    const float gx = (float)m;
    const float gy = (float)n;
    const float inv7 = 1.0f / 7.0f;

    const float cx1 = (pv[0] + gx) * inv7, cy1 = (pv[1] + gy) * inv7;
    const float hw1 = 0.5f * pv[2],        hh1 = 0.5f * pv[3];
    const float a1x1 = cx1 - hw1, a1y1 = cy1 - hh1, a1x2 = cx1 + hw1, a1y2 = cy1 + hh1;
    const float cx2 = (pv[5] + gx) * inv7, cy2 = (pv[6] + gy) * inv7;
    const float hw2 = 0.5f * pv[7],        hh2 = 0.5f * pv[8];
    const float a2x1 = cx2 - hw2, a2y1 = cy2 - hh2, a2x2 = cx2 + hw2, a2y2 = cy2 + hh2;
    const float cxg = (lv[0] + gx) * inv7, cyg = (lv[1] + gy) * inv7;
    const float hwg = 0.5f * lv[2],        hhg = 0.5f * lv[3];
    const float bx1 = cxg - hwg, by1 = cyg - hhg, bx2 = cxg + hwg, by2 = cyg + hhg;

    const float area_g = (bx2 - bx1) * (by2 - by1);

    float ix1 = fmaxf(a1x1, bx1), iy1 = fmaxf(a1y1, by1);
    float ix2 = fminf(a1x2, bx2), iy2 = fminf(a1y2, by2);
    float inter1 = fmaxf(ix2 - ix1, 0.0f) * fmaxf(iy2 - iy1, 0.0f);
    float area1  = (a1x2 - a1x1) * (a1y2 - a1y1);
    float iou1 = (inter1 > 0.0f) ? inter1 / (area1 + area_g - inter1) : 0.0f;

    ix1 = fmaxf(a2x1, bx1); iy1 = fmaxf(a2y1, by1);
    ix2 = fminf(a2x2, bx2); iy2 = fminf(a2y2, by2);
    float inter2 = fmaxf(ix2 - ix1, 0.0f) * fmaxf(iy2 - iy1, 0.0f);
    float area2  = (a2x2 - a2x1) * (a2y2 - a2y1);
    float iou2 = (inter2 > 0.0f) ? inter2 / (area2 + area_g - inter2) : 0.0f;

    const bool resp1 = iou1 > iou2;
    const float obj = (lv[4] == 1.0f) ? 1.0f : 0.0f;

    const float coor1 = sq(pv[0] - lv[0]) + sq(pv[1] - lv[1])
                      + sq(sqrtf(pv[2]) - sqrtf(lv[2])) + sq(sqrtf(pv[3]) - sqrtf(lv[3]));
    const float coor2 = sq(pv[5] - lv[5]) + sq(pv[6] - lv[6])
                      + sq(sqrtf(pv[7]) - sqrtf(lv[7])) + sq(sqrtf(pv[8]) - sqrtf(lv[8]));
    const float coor = resp1 ? coor1 : coor2;

    const float e1 = sq(pv[4] - iou1);
    const float e2 = sq(pv[9] - iou2);
    const float obj_conf   = resp1 ? e1 : e2;
    const float noobj_resp = resp1 ? e2 : e1;

    return obj * (5.0f * coor + obj_conf + 0.5f * noobj_resp)
         + (1.0f - obj) * 0.5f * (pv[4] * pv[4] + pv[9] * pv[9]);
}

__global__ __launch_bounds__(TPB) void yolo_loss_partial(
    const float* __restrict__ pred,
    const float* __restrict__ lab,
    float* __restrict__ ws)
{
    __shared__ float sbox_p[NIMG][BOX_F];   // 15680 B
    __shared__ float sbox_l[NIMG][BOX_F];   // 15680 B
    __shared__ float wsum[TPB / 64];

    const int t = threadIdx.x;
    const size_t blk_f = (size_t)blockIdx.x * NIMG * IMG_F;
    const float2* gp2 = (const float2*)(pred + blk_f);
    const float2* gl2 = (const float2*)(lab  + blk_f);

    // ---- stage box regions ([0,490) floats of each image, both tensors) ----
#pragma unroll
    for (int it = 0; it <= STAGE_FULL; ++it) {
        const int j = t + it * TPB;
        if (it < STAGE_FULL || t < STAGE_TAIL) {
            const int is_l  = j >= NIMG * BOX_V2;
            const int local = j - is_l * (NIMG * BOX_V2);
            const int img   = local / BOX_V2;
            const int k     = local - img * BOX_V2;
            const float2 v = (is_l ? gl2 : gp2)[img * IMG_V2 + k];
            float* dst = (is_l ? &sbox_l[img][2 * k] : &sbox_p[img][2 * k]);
            *(float2*)dst = v;
        }
    }
    __syncthreads();

    float acc = 0.0f;

    // ---- phase 1: stream cls region (channels 10..29), obj from LDS ----
#pragma unroll
    for (int i = 0; i < NIMG; ++i) {
        const float2* pc = gp2 + i * IMG_V2 + BOX_V2;
        const float2* lc = gl2 + i * IMG_V2 + BOX_V2;
        const float* objp = &sbox_l[i][4 * GG];
        {
            const float2 p = pc[t], l = lc[t];
            const int n0 = 2 * t;
            const int c0 = n0 % 49;
            const int c1 = (c0 == 48) ? 0 : c0 + 1;
            const float w0 = (objp[c0] == 1.0f) ? 1.0f : 0.0f;
            const float w1 = (objp[c1] == 1.0f) ? 1.0f : 0.0f;
            const float d0 = p.x - l.x, d1 = p.y - l.y;
            acc += w0 * d0 * d0 + w1 * d1 * d1;
        }
        if (t < CLS_V2 - TPB) {   // t < 234
            const int u = t + TPB;
            const float2 p = pc[u], l = lc[u];
            const int n0 = 2 * u;
            const int c0 = n0 % 49;
            const int c1 = (c0 == 48) ? 0 : c0 + 1;
            const float w0 = (objp[c0] == 1.0f) ? 1.0f : 0.0f;
            const float w1 = (objp[c1] == 1.0f) ? 1.0f : 0.0f;
            const float d0 = p.x - l.x, d1 = p.y - l.y;
            acc += w0 * d0 * d0 + w1 * d1 * d1;
        }
    }

    // ---- phase 2: per-cell box loss from LDS (392 cells) ----
    {
        const int img  = t / GG;
        const int cell = t - img * GG;
        if (t < NCELL)  // t < 392, always true for t < 256
            acc += cell_box_loss(sbox_p[img], sbox_l[img], cell);
    }
    if (t < NCELL - TPB) {   // t < 136
        const int u    = t + TPB;
        const int img  = u / GG;
        const int cell = u - img * GG;
        acc += cell_box_loss(sbox_p[img], sbox_l[img], cell);
    }

    // ---- reduce: wave(64) shuffle -> LDS -> one partial per block ----
#pragma unroll
    for (int off = 32; off > 0; off >>= 1) acc += __shfl_down(acc, off, 64);

    const int lane = t & 63;
    const int wid  = t >> 6;
    if (lane == 0) wsum[wid] = acc;
    __syncthreads();
    if (t == 0) ws[blockIdx.x] = wsum[0] + wsum[1] + wsum[2] + wsum[3];
}

__global__ __launch_bounds__(TPB) void yolo_loss_final(
    const float* __restrict__ ws, float* __restrict__ out)
{
    const int t = threadIdx.x;
    const float4* w4 = (const float4*)ws;
    float4 a = make_float4(0.f, 0.f, 0.f, 0.f);
#pragma unroll
    for (int j = 0; j < NBLK / 4 / TPB; ++j) {   // 2048/4/256 = 2 exact
        float4 x = w4[t + j * TPB];
        a.x += x.x; a.y += x.y; a.z += x.z; a.w += x.w;
    }
    float v = (a.x + a.y) + (a.z + a.w);
#pragma unroll
    for (int off = 32; off > 0; off >>= 1) v += __shfl_down(v, off, 64);

    __shared__ float wsum[TPB / 64];
    const int lane = t & 63;
    const int wid  = t >> 6;
    if (lane == 0) wsum[wid] = v;
    __syncthreads();
    if (t == 0) {
        // faithful reference quirk: divide by (N-1) == 6, not batch size
        out[0] = (wsum[0] + wsum[1] + wsum[2] + wsum[3]) * (1.0f / 6.0f);
    }
}

extern "C" void kernel_launch(void* const* d_in, const int* in_sizes, int n_in,
                              void* d_out, int out_size, void* d_ws, size_t ws_size,
                              hipStream_t stream) {
    const float* pred = (const float*)d_in[0];
    const float* lab  = (const float*)d_in[1];
    float* ws  = (float*)d_ws;
    float* out = (float*)d_out;

    yolo_loss_partial<<<NBLK, TPB, 0, stream>>>(pred, lab, ws);
    yolo_loss_final<<<1, TPB, 0, stream>>>(ws, out);
}